// Round 1
// 199.074 us; speedup vs baseline: 1.0596x; 1.0596x over previous
//
#include <hip/hip_runtime.h>
#include <stdint.h>

typedef unsigned short u16;
typedef short short8 __attribute__((ext_vector_type(8)));
typedef float f32x4 __attribute__((ext_vector_type(4)));
typedef float f32x16 __attribute__((ext_vector_type(16)));
typedef float f32x2 __attribute__((ext_vector_type(2)));

// ---------- helpers ----------
__device__ __forceinline__ u16 f2bf_fast(float f) {
  union { float f; uint32_t u; } x;
  x.f = f;
  return (u16)((x.u + 0x8000u) >> 16);
}

__device__ __forceinline__ uint32_t pack2bf(float lo, float hi) {
  union { float f; uint32_t u; } a, b;
  a.f = lo; b.f = hi;
  return __builtin_amdgcn_perm(b.u + 0x8000u, a.u + 0x8000u, 0x07060302u);
}

__device__ __forceinline__ float bf2f(uint32_t u) {
  union { uint32_t u; float f; } x;
  x.u = u << 16;
  return x.f;
}

// v_cvt_pk_bf16_f32: D = {bf16(lo), bf16(hi)} (RNE). No builtin on gfx950.
__device__ __forceinline__ uint32_t cvtpk(float lo, float hi) {
  uint32_t r;
  asm("v_cvt_pk_bf16_f32 %0, %1, %2" : "=v"(r) : "v"(lo), "v"(hi));
  return r;
}

// v_permlane32_swap_b32: a.row1 <-> b.row0 (rows = 32-lane halves).
__device__ __forceinline__ void permswap(uint32_t& a, uint32_t& b) {
  asm("v_permlane32_swap_b32 %0, %1" : "+v"(a), "+v"(b));
}

__device__ __forceinline__ void gload_lds16(const void* g, void* l) {
  __builtin_amdgcn_global_load_lds(
      (const __attribute__((address_space(1))) void*)g,
      (__attribute__((address_space(3))) void*)l, 16, 0, 0);
}

__device__ __forceinline__ f32x4 mfma16(short8 a, short8 b, f32x4 c) {
  return __builtin_amdgcn_mfma_f32_16x16x32_bf16(a, b, c, 0, 0, 0);
}

__device__ __forceinline__ f32x16 mfma32(short8 a, short8 b, f32x16 c) {
  return __builtin_amdgcn_mfma_f32_32x32x16_bf16(a, b, c, 0, 0, 0);
}

// P32 packed fragment load: granule = ((tile*32+kc)*64+lane)*8 u16
__device__ __forceinline__ short8 ldfrag(const u16* base, int tile, int kc,
                                         int lane) {
  return *(const short8*)(base + ((((tile << 5) + kc) << 6) + lane) * 8);
}

#define QSCALE 0.18033688011112042f

// ---------- pack fp32 -> bf16 P32 fragment layout ----------
// P32: pack[((rt*32+kc)*64+ln)*8+j] = M[rt*16+(ln&15)][kc*32+(ln>>4)*8+j]
// rt 0..255 -> x (4096x1024) into xp; rt 256..511 -> [Wq;Wk;Wv;Wo] into wp.
__global__ void pack_all(const float* __restrict__ x, const float* __restrict__ wq,
                         const float* __restrict__ wk, const float* __restrict__ wv,
                         const float* __restrict__ wo, u16* __restrict__ xp,
                         u16* __restrict__ wp) {
  const int gi = blockIdx.x * 256 + threadIdx.x;  // granule id, 0..1048575
  const int lane = gi & 63;
  const int kc = (gi >> 6) & 31;
  const int rt = gi >> 11;  // row tile 0..511
  const int col = kc * 32 + (lane >> 4) * 8;
  const float* src;
  int row;
  if (rt < 256) {
    src = x;
    row = rt * 16 + (lane & 15);
  } else {
    const int wti = rt - 256;             // 0..255
    const int widx = wti >> 6;            // which weight
    src = (widx == 0) ? wq : (widx == 1) ? wk : (widx == 2) ? wv : wo;
    row = (wti & 63) * 16 + (lane & 15);
  }
  const float4* p = (const float4*)(src + (size_t)row * 1024 + col);
  const float4 v0 = p[0], v1 = p[1];
  uint4 o;
  o.x = pack2bf(v0.x, v0.y);
  o.y = pack2bf(v0.z, v0.w);
  o.z = pack2bf(v1.x, v1.y);
  o.w = pack2bf(v1.z, v1.w);
  u16* dst = (rt < 256) ? xp : wp;
  const int og = (rt < 256) ? gi : gi - 524288;
  ((uint4*)dst)[og] = o;
}

// ---------- LDS-free projection GEMM (QK + V^T merged) ----------
__global__ __launch_bounds__(256, 3) void proj_qkv(
    const u16* __restrict__ xp, const u16* __restrict__ wp,
    const float* __restrict__ bq, const float* __restrict__ bk,
    const float* __restrict__ bv, u16* __restrict__ qw, u16* __restrict__ kw,
    u16* __restrict__ vw) {
  const int gid = blockIdx.x * 4 + (threadIdx.x >> 6);
  const int lane = threadIdx.x & 63;
  const int quad = lane >> 4, l15 = lane & 15;
  const bool isQK = gid < 2048;
  int at0, bt0, bm, bn;
  const u16 *Ap, *Bp;
  if (isQK) {
    bn = gid >> 6; bm = gid & 63;
    Ap = xp; at0 = bm * 4;            // x row-tiles
    Bp = wp; bt0 = bn * 4;            // Wq|Wk tiles 0..127
  } else {
    const int h = gid - 2048;
    bn = h & 63; bm = h >> 6;
    Ap = wp; at0 = 128 + bm * 4;      // Wv tiles 128..191
    Bp = xp; bt0 = bn * 4;            // x row-tiles (seq)
  }

  f32x4 acc[4][4] = {};
  short8 af[2][4], bf[2][4];
#pragma unroll
  for (int mt = 0; mt < 4; ++mt) af[0][mt] = ldfrag(Ap, at0 + mt, 0, lane);
#pragma unroll
  for (int nt = 0; nt < 4; ++nt) bf[0][nt] = ldfrag(Bp, bt0 + nt, 0, lane);

#pragma unroll 4
  for (int kc = 0; kc < 32; ++kc) {
    const int cur = kc & 1, nxt = cur ^ 1;
    if (kc < 31) {
#pragma unroll
      for (int mt = 0; mt < 4; ++mt)
        af[nxt][mt] = ldfrag(Ap, at0 + mt, kc + 1, lane);
#pragma unroll
      for (int nt = 0; nt < 4; ++nt)
        bf[nxt][nt] = ldfrag(Bp, bt0 + nt, kc + 1, lane);
    }
#pragma unroll
    for (int mt = 0; mt < 4; ++mt)
#pragma unroll
      for (int nt = 0; nt < 4; ++nt)
        acc[mt][nt] = mfma16(af[cur][mt], bf[cur][nt], acc[mt][nt]);
  }

#pragma unroll
  for (int nt = 0; nt < 4; ++nt) {
    const int n = bn * 64 + nt * 16 + l15;
#pragma unroll
    for (int mt = 0; mt < 4; ++mt)
#pragma unroll
      for (int r = 0; r < 4; ++r) {
        const int m = bm * 64 + mt * 16 + quad * 4 + r;
        const float a = acc[mt][nt][r];
        if (isQK) {
          const bool isQ = (bn < 16);
          const int nn = isQ ? n : n - 1024;
          const float v = isQ ? (a + bq[nn]) * QSCALE : a + bk[nn];
          u16* op = isQ ? qw : kw;
          const int b = m >> 11, s = m & 2047, hh = nn >> 6, d = nn & 63;
          op[((size_t)((b * 16 + hh) * 2048 + s)) * 64 + d] = f2bf_fast(v);
        } else {
          const float v = a + bv[m];
          const int b = n >> 11, s = n & 2047;
          vw[((size_t)(b * 1024 + m)) * 2048 + s] = f2bf_fast(v);
        }
      }
  }
}

// ---------- flash attention, 32x32-MFMA restructure ----------
// Swapped QK^T (S^T = K.Q^T) via mfma_f32_32x32x16_bf16 -> per-lane holds a
// 32-q-wide fragment (col=lane&31). Softmax fully in-register; P repacked to
// the PV B-fragment with v_cvt_pk_bf16_f32 + v_permlane32_swap_b32 (T12).
// PV also 32x32x16. Outputs packed o-partials (P32 aw-shape) + l-partials.
__global__ __launch_bounds__(256, 4) void attn_kernel(
    const u16* __restrict__ Q, const u16* __restrict__ Kt,
    const u16* __restrict__ Vt, u16* __restrict__ op0, u16* __restrict__ op1,
    float* __restrict__ lp) {
  __shared__ __align__(16) u16 Sm[16384];  // 32 KB
  const int tid = threadIdx.x, lane = tid & 63, w = tid >> 6;
  const int l31 = lane & 31, hi = lane >> 5, l7 = lane & 7;
  const int qt = blockIdx.x;
  const int bh = blockIdx.y >> 1;
  const int ks = blockIdx.y & 1;

  const char* Qb = (const char*)(Q + ((size_t)bh * 2048 + qt * 128) * 64);
  const char* Kb = (const char*)(Kt + ((size_t)bh * 2048 + ks * 1024) * 64);
  const char* Vb = (const char*)(Vt + (size_t)bh * 64 * 2048 + ks * 1024);

  auto stageKV = [&](int kt, int b) {
    u16* Kl = Sm + b * 4096;
    u16* Vl = Sm + 8192 + b * 4096;
#pragma unroll
    for (int i = 0; i < 2; ++i) {
      const int G = (w * 2 + i) * 64 + lane;
      const int r = G >> 3, sl = G & 7;
      gload_lds16(Kb + (size_t)(kt * 64 + r) * 128 + ((sl ^ (r & 7)) * 16),
                  &Kl[G * 8]);
      gload_lds16(Vb + (size_t)r * 4096 + kt * 128 + ((sl ^ (r & 7)) * 16),
                  &Vl[G * 8]);
    }
  };

#pragma unroll
  for (int i = 0; i < 4; ++i) {
    const int G = (w * 4 + i) * 64 + lane;
    const int row = G >> 3, sl = G & 7;
    u16* qdst = (G < 512) ? (Sm + 4096) : (Sm + 12288);
    gload_lds16(Qb + (size_t)row * 128 + ((sl ^ (row & 7)) * 16),
                &qdst[(G & 511) * 8]);
  }
  stageKV(0, 0);
  __syncthreads();

  // Q fragment (B-operand of 32x32x16): q = l31, d = ds*16 + hi*8 + j
  const u16* qreg = (w < 2) ? (Sm + 4096) : (Sm + 12288);
  const int qr0 = (w & 1) * 32;
  short8 aq[4];
#pragma unroll
  for (int ds = 0; ds < 4; ++ds)
    aq[ds] = *(const short8*)&qreg[(qr0 + l31) * 64 + (((ds << 1) + hi) ^ l7) * 8];
  __syncthreads();

  f32x16 ot[2] = {};   // O^T acc: dt in {0,1}, d = dt*32 + (reg&3)+8*(reg>>2)+4*hi
  f32x2 l2 = {0.f, 0.f};

  for (int kt = 0; kt < 16; ++kt) {
    const int buf = kt & 1;
    if (kt < 15) stageKV(kt + 1, buf ^ 1);
    const u16* Kl = Sm + buf * 4096;
    const u16* Vl = Sm + 8192 + buf * 4096;

#pragma unroll
    for (int t = 0; t < 2; ++t) {  // two 32-k S^T tiles per 64-k LDS tile
      f32x16 st = {};
#pragma unroll
      for (int ds = 0; ds < 4; ++ds) {
        short8 kf = *(const short8*)&Kl[(t * 32 + l31) * 64 +
                                        (((ds << 1) + hi) ^ l7) * 8];
        st = mfma32(kf, aq[ds], st);
      }
      float e[16];
#pragma unroll
      for (int i = 0; i < 16; ++i) e[i] = __builtin_amdgcn_exp2f(st[i]);
#pragma unroll
      for (int i = 0; i < 8; ++i) l2 += (f32x2){e[2 * i], e[2 * i + 1]};

      // pack to PV B-fragments: pairing (e0,e1)x(e4,e5) etc per T12
      uint32_t p01 = cvtpk(e[0], e[1]),   p23 = cvtpk(e[2], e[3]);
      uint32_t p45 = cvtpk(e[4], e[5]),   p67 = cvtpk(e[6], e[7]);
      uint32_t p89 = cvtpk(e[8], e[9]),   pAB = cvtpk(e[10], e[11]);
      uint32_t pCD = cvtpk(e[12], e[13]), pEF = cvtpk(e[14], e[15]);
      permswap(p01, p45);  // -> ksub0 w0, w2
      permswap(p23, p67);  // -> ksub0 w1, w3
      permswap(p89, pCD);  // -> ksub1 w0, w2
      permswap(pAB, pEF);  // -> ksub1 w1, w3
      union { uint32_t u[4]; short8 s; } b0, b1;
      b0.u[0] = p01; b0.u[1] = p23; b0.u[2] = p45; b0.u[3] = p67;
      b1.u[0] = p89; b1.u[1] = pAB; b1.u[2] = pCD; b1.u[3] = pEF;

#pragma unroll
      for (int dt = 0; dt < 2; ++dt) {
#pragma unroll
        for (int s2 = 0; s2 < 2; ++s2) {
          short8 vf = *(const short8*)&Vl[(dt * 32 + l31) * 64 +
                                          ((((t * 2 + s2) << 1) + hi) ^ l7) * 8];
          ot[dt] = mfma32(vf, s2 ? b1.s : b0.s, ot[dt]);
        }
      }
    }
    if (kt < 15) __syncthreads();
  }

  // epilogue: packed o-partials + l-partials
  const int b = bh >> 4, h = bh & 15;
  u16* op = ks ? op1 : op0;
  float l = l2.x + l2.y;
  l += __shfl_xor(l, 32);
  const int srow = qt * 128 + w * 32 + l31;
  if (hi == 0) lp[((size_t)(ks * 32 + bh)) * 2048 + srow] = l;
  const int rt = b * 128 + qt * 8 + w * 2 + (l31 >> 4);  // row = rt*16 + (lane&15)
#pragma unroll
  for (int dt = 0; dt < 2; ++dt) {
    const int kc = h * 2 + dt;
#pragma unroll
    for (int g = 0; g < 4; ++g) {  // reg group: d = dt*32 + (reg&3) + 8*g + 4*hi
      const int ln = (lane & 15) + 16 * g;
      uint2 ov;
      ov.x = cvtpk(ot[dt][4 * g + 0], ot[dt][4 * g + 1]);
      ov.y = cvtpk(ot[dt][4 * g + 2], ot[dt][4 * g + 3]);
      *(uint2*)(op + ((size_t)((rt * 32 + kc) * 64 + ln)) * 8 + hi * 4) = ov;
    }
  }
}

// ---------- combine (packed granule-wise): awp = (o0+o1)/(l0+l1) ----------
__global__ void attn_combine(const u16* __restrict__ op0,
                             const u16* __restrict__ op1,
                             const float* __restrict__ lp,
                             u16* __restrict__ awp) {
  const int g = blockIdx.x * 256 + threadIdx.x;  // granule 0..524287
  const int ln = g & 63;
  const int kc = (g >> 6) & 31;
  const int rt = g >> 11;
  const int row = rt * 16 + (ln & 15);
  const int b = row >> 11, s = row & 2047;
  const int h = kc >> 1;
  const int lidx = (b * 16 + h) * 2048 + s;
  const float inv = __builtin_amdgcn_rcpf(lp[lidx] + lp[lidx + 65536]);
  const uint4 a0 = ((const uint4*)op0)[g];
  const uint4 a1 = ((const uint4*)op1)[g];
  uint4 o;
  o.x = pack2bf((bf2f(a0.x) + bf2f(a1.x)) * inv,
                (bf2f(a0.x >> 16) + bf2f(a1.x >> 16)) * inv);
  o.y = pack2bf((bf2f(a0.y) + bf2f(a1.y)) * inv,
                (bf2f(a0.y >> 16) + bf2f(a1.y >> 16)) * inv);
  o.z = pack2bf((bf2f(a0.z) + bf2f(a1.z)) * inv,
                (bf2f(a0.z >> 16) + bf2f(a1.z >> 16)) * inv);
  o.w = pack2bf((bf2f(a0.w) + bf2f(a1.w)) * inv,
                (bf2f(a0.w >> 16) + bf2f(a1.w >> 16)) * inv);
  ((uint4*)awp)[g] = o;
}

// ---------- LDS-free out projection: C[4096,1024] f32 = aw @ Wo^T + bo ----------
__global__ __launch_bounds__(256, 3) void out_proj(const u16* __restrict__ awp,
                                                   const u16* __restrict__ wp,
                                                   const float* __restrict__ bo,
                                                   float* __restrict__ out) {
  const int gid = blockIdx.x * 4 + (threadIdx.x >> 6);
  const int lane = threadIdx.x & 63;
  const int quad = lane >> 4, l15 = lane & 15;
  const int bm = gid & 63, bnn = gid >> 6;
  const int at0 = bm * 4, bt0 = 192 + bnn * 2;

  f32x4 acc[4][2] = {};
  short8 af[2][4], bf[2][2];
#pragma unroll
  for (int mt = 0; mt < 4; ++mt) af[0][mt] = ldfrag(awp, at0 + mt, 0, lane);
#pragma unroll
  for (int nt = 0; nt < 2; ++nt) bf[0][nt] = ldfrag(wp, bt0 + nt, 0, lane);

#pragma unroll 4
  for (int kc = 0; kc < 32; ++kc) {
    const int cur = kc & 1, nxt = cur ^ 1;
    if (kc < 31) {
#pragma unroll
      for (int mt = 0; mt < 4; ++mt)
        af[nxt][mt] = ldfrag(awp, at0 + mt, kc + 1, lane);
#pragma unroll
      for (int nt = 0; nt < 2; ++nt)
        bf[nxt][nt] = ldfrag(wp, bt0 + nt, kc + 1, lane);
    }
#pragma unroll
    for (int mt = 0; mt < 4; ++mt)
#pragma unroll
      for (int nt = 0; nt < 2; ++nt)
        acc[mt][nt] = mfma16(af[cur][mt], bf[cur][nt], acc[mt][nt]);
  }

#pragma unroll
  for (int nt = 0; nt < 2; ++nt) {
    const int n = bnn * 32 + nt * 16 + l15;
    const float bb = bo[n];
#pragma unroll
    for (int mt = 0; mt < 4; ++mt)
#pragma unroll
      for (int r = 0; r < 4; ++r) {
        const int m = bm * 64 + mt * 16 + quad * 4 + r;
        out[(size_t)m * 1024 + n] = acc[mt][nt][r] + bb;
      }
  }
}

// ---------- launch ----------
extern "C" void kernel_launch(void* const* d_in, const int* in_sizes, int n_in,
                              void* d_out, int out_size, void* d_ws, size_t ws_size,
                              hipStream_t stream) {
  const float* x  = (const float*)d_in[0];
  const float* Wq = (const float*)d_in[1];
  const float* bq = (const float*)d_in[2];
  const float* Wk = (const float*)d_in[3];
  const float* bk = (const float*)d_in[4];
  const float* Wv = (const float*)d_in[5];
  const float* bv = (const float*)d_in[6];
  const float* Wo = (const float*)d_in[7];
  const float* bo = (const float*)d_in[8];

  const size_t M4 = (size_t)4 * 1024 * 1024;
  u16* xp  = (u16*)d_ws;     // 4M elems; dead after proj -> reused as op0
  u16* wp  = xp + M4;        // packed [Wq;Wk;Wv;Wo]
  u16* qw  = wp + M4;
  u16* kw  = qw + M4;
  u16* vw  = kw + M4;
  u16* op1 = vw + M4;
  u16* awp = op1 + M4;
  float* lp = (float*)(awp + M4);  // 128K floats
  u16* op0 = xp;

  pack_all<<<4096, 256, 0, stream>>>(x, Wq, Wk, Wv, Wo, xp, wp);

  proj_qkv<<<768, 256, 0, stream>>>(xp, wp, bq, bk, bv, qw, kw, vw);

  attn_kernel<<<dim3(16, 64), 256, 0, stream>>>(qw, kw, vw, op0, op1, lp);

  attn_combine<<<2048, 256, 0, stream>>>(op0, op1, lp, awp);

  out_proj<<<512, 256, 0, stream>>>(awp, wp, bo, (float*)d_out);
}

// Round 2
// 192.879 us; speedup vs baseline: 1.0936x; 1.0321x over previous
//
#include <hip/hip_runtime.h>
#include <stdint.h>

typedef unsigned short u16;
typedef short short8 __attribute__((ext_vector_type(8)));
typedef float f32x4 __attribute__((ext_vector_type(4)));
typedef float f32x16 __attribute__((ext_vector_type(16)));
typedef float f32x2 __attribute__((ext_vector_type(2)));

// ---------- helpers ----------
__device__ __forceinline__ u16 f2bf_fast(float f) {
  union { float f; uint32_t u; } x;
  x.f = f;
  return (u16)((x.u + 0x8000u) >> 16);
}

__device__ __forceinline__ uint32_t pack2bf(float lo, float hi) {
  union { float f; uint32_t u; } a, b;
  a.f = lo; b.f = hi;
  return __builtin_amdgcn_perm(b.u + 0x8000u, a.u + 0x8000u, 0x07060302u);
}

__device__ __forceinline__ float bf2f(uint32_t u) {
  union { uint32_t u; float f; } x;
  x.u = u << 16;
  return x.f;
}

// v_cvt_pk_bf16_f32: D = {bf16(lo), bf16(hi)} (RNE). No builtin on gfx950.
__device__ __forceinline__ uint32_t cvtpk(float lo, float hi) {
  uint32_t r;
  asm("v_cvt_pk_bf16_f32 %0, %1, %2" : "=v"(r) : "v"(lo), "v"(hi));
  return r;
}

// v_permlane32_swap_b32: a.row1 <-> b.row0 (rows = 32-lane halves).
__device__ __forceinline__ void permswap(uint32_t& a, uint32_t& b) {
  asm("v_permlane32_swap_b32 %0, %1" : "+v"(a), "+v"(b));
}

__device__ __forceinline__ void gload_lds16(const void* g, void* l) {
  __builtin_amdgcn_global_load_lds(
      (const __attribute__((address_space(1))) void*)g,
      (__attribute__((address_space(3))) void*)l, 16, 0, 0);
}

__device__ __forceinline__ f32x4 mfma16(short8 a, short8 b, f32x4 c) {
  return __builtin_amdgcn_mfma_f32_16x16x32_bf16(a, b, c, 0, 0, 0);
}

__device__ __forceinline__ f32x16 mfma32(short8 a, short8 b, f32x16 c) {
  return __builtin_amdgcn_mfma_f32_32x32x16_bf16(a, b, c, 0, 0, 0);
}

#define QSCALE 0.18033688011112042f

// ---------- pack fp32 -> bf16 P32 fragment layout ----------
// P32: pack[((rt*32+kc)*64+ln)*8+j] = M[rt*16+(ln&15)][kc*32+(ln>>4)*8+j]
// rt 0..255 -> x (4096x1024) into xp; rt 256..511 -> [Wq;Wk;Wv;Wo] into wp.
__global__ void pack_all(const float* __restrict__ x, const float* __restrict__ wq,
                         const float* __restrict__ wk, const float* __restrict__ wv,
                         const float* __restrict__ wo, u16* __restrict__ xp,
                         u16* __restrict__ wp) {
  const int gi = blockIdx.x * 256 + threadIdx.x;  // granule id, 0..1048575
  const int lane = gi & 63;
  const int kc = (gi >> 6) & 31;
  const int rt = gi >> 11;  // row tile 0..511
  const int col = kc * 32 + (lane >> 4) * 8;
  const float* src;
  int row;
  if (rt < 256) {
    src = x;
    row = rt * 16 + (lane & 15);
  } else {
    const int wti = rt - 256;             // 0..255
    const int widx = wti >> 6;            // which weight
    src = (widx == 0) ? wq : (widx == 1) ? wk : (widx == 2) ? wv : wo;
    row = (wti & 63) * 16 + (lane & 15);
  }
  const float4* p = (const float4*)(src + (size_t)row * 1024 + col);
  const float4 v0 = p[0], v1 = p[1];
  uint4 o;
  o.x = pack2bf(v0.x, v0.y);
  o.y = pack2bf(v0.z, v0.w);
  o.z = pack2bf(v1.x, v1.y);
  o.w = pack2bf(v1.z, v1.w);
  u16* dst = (rt < 256) ? xp : wp;
  const int og = (rt < 256) ? gi : gi - 524288;
  ((uint4*)dst)[og] = o;
}

// ---------- LDS-staged 128x128 projection GEMM (m97 structure) ----------
// P32-packed operands: staging is granule-linear (gload_lds dest =
// uniform + lane*16B), ds_read_b128 reads back the exact fragment -> no
// swizzle, conflict-free. BK=64 (2 kc-granules), 2 barriers/K-step.
// works 0..511:  QK: C = x @ [Wq|Wk]^T, block (bm2 0..31, bn2 0..15).
// works 512..767: V: C = Wv @ x^T,      block (bm2 0..7,  bn2 0..31).
__global__ __launch_bounds__(256, 3) void proj_qkv(
    const u16* __restrict__ xp, const u16* __restrict__ wp,
    const float* __restrict__ bq, const float* __restrict__ bk,
    const float* __restrict__ bv, u16* __restrict__ qw, u16* __restrict__ kw,
    u16* __restrict__ vw) {
  __shared__ __align__(16) u16 As[8192];   // 16 KB: 8 row-tiles x 2 kc
  __shared__ __align__(16) u16 Bs[8192];   // 16 KB
  const int tid = threadIdx.x, lane = tid & 63, w = tid >> 6;
  const int quad = lane >> 4, l15 = lane & 15;

  // bijective XCD-chunked swizzle: 768 blocks, 96 per XCD
  const int bid = blockIdx.x;
  const int work = (bid & 7) * 96 + (bid >> 3);
  const bool isQK = work < 512;
  int at0, bt0, bm2, bn2;
  const u16 *Ap, *Bp;
  if (isQK) {
    bm2 = work >> 4; bn2 = work & 15;          // bm-major: B panel L2-resident
    Ap = xp; at0 = bm2 * 8;
    Bp = wp; bt0 = bn2 * 8;                    // Wq|Wk tiles 0..127
  } else {
    const int h = work - 512;
    bm2 = h >> 5; bn2 = h & 31;
    Ap = wp; at0 = 128 + bm2 * 8;              // Wv tiles 128..191
    Bp = xp; bt0 = bn2 * 8;                    // x row-tiles (seq)
  }
  const int wr = w >> 1, wc = w & 1;
  const int bm = bm2 * 2 + wr, bn = bn2 * 2 + wc;  // 64-row/col units

  f32x4 acc[4][4] = {};

  for (int ks = 0; ks < 16; ++ks) {
    const int kc0 = ks * 2;
    // stage 32 granules (16 A + 16 B), 8 per wave
#pragma unroll
    for (int i = 0; i < 8; ++i) {
      const int g = w * 8 + i;                 // 0..31
      const int gg = g & 15, t = gg >> 1, c = gg & 1;
      const u16* src = (g < 16)
          ? (Ap + ((((at0 + t) << 5) + kc0 + c) * 64 + lane) * 8)
          : (Bp + ((((bt0 + t) << 5) + kc0 + c) * 64 + lane) * 8);
      u16* dst = ((g < 16) ? As : Bs) + (gg * 64 + lane) * 8;
      gload_lds16(src, dst);
    }
    __syncthreads();

    short8 af[4][2], bf[4][2];
#pragma unroll
    for (int mt = 0; mt < 4; ++mt)
#pragma unroll
      for (int c = 0; c < 2; ++c)
        af[mt][c] = *(const short8*)&As[((((wr * 4 + mt) << 1) + c) * 64 + lane) * 8];
#pragma unroll
    for (int nt = 0; nt < 4; ++nt)
#pragma unroll
      for (int c = 0; c < 2; ++c)
        bf[nt][c] = *(const short8*)&Bs[((((wc * 4 + nt) << 1) + c) * 64 + lane) * 8];

#pragma unroll
    for (int c = 0; c < 2; ++c)
#pragma unroll
      for (int mt = 0; mt < 4; ++mt)
#pragma unroll
        for (int nt = 0; nt < 4; ++nt)
          acc[mt][nt] = mfma16(af[mt][c], bf[nt][c], acc[mt][nt]);
    __syncthreads();
  }

#pragma unroll
  for (int nt = 0; nt < 4; ++nt) {
    const int n = bn * 64 + nt * 16 + l15;
#pragma unroll
    for (int mt = 0; mt < 4; ++mt)
#pragma unroll
      for (int r = 0; r < 4; ++r) {
        const int m = bm * 64 + mt * 16 + quad * 4 + r;
        const float a = acc[mt][nt][r];
        if (isQK) {
          const bool isQ = (bn < 16);
          const int nn = isQ ? n : n - 1024;
          const float v = isQ ? (a + bq[nn]) * QSCALE : a + bk[nn];
          u16* op = isQ ? qw : kw;
          const int b = m >> 11, s = m & 2047, hh = nn >> 6, d = nn & 63;
          op[((size_t)((b * 16 + hh) * 2048 + s)) * 64 + d] = f2bf_fast(v);
        } else {
          const float v = a + bv[m];
          const int b = n >> 11, s = n & 2047;
          vw[((size_t)(b * 1024 + m)) * 2048 + s] = f2bf_fast(v);
        }
      }
  }
}

// ---------- flash attention, 32x32-MFMA (unchanged from R1) ----------
__global__ __launch_bounds__(256, 4) void attn_kernel(
    const u16* __restrict__ Q, const u16* __restrict__ Kt,
    const u16* __restrict__ Vt, u16* __restrict__ op0, u16* __restrict__ op1,
    float* __restrict__ lp) {
  __shared__ __align__(16) u16 Sm[16384];  // 32 KB
  const int tid = threadIdx.x, lane = tid & 63, w = tid >> 6;
  const int l31 = lane & 31, hi = lane >> 5, l7 = lane & 7;
  const int qt = blockIdx.x;
  const int bh = blockIdx.y >> 1;
  const int ks = blockIdx.y & 1;

  const char* Qb = (const char*)(Q + ((size_t)bh * 2048 + qt * 128) * 64);
  const char* Kb = (const char*)(Kt + ((size_t)bh * 2048 + ks * 1024) * 64);
  const char* Vb = (const char*)(Vt + (size_t)bh * 64 * 2048 + ks * 1024);

  auto stageKV = [&](int kt, int b) {
    u16* Kl = Sm + b * 4096;
    u16* Vl = Sm + 8192 + b * 4096;
#pragma unroll
    for (int i = 0; i < 2; ++i) {
      const int G = (w * 2 + i) * 64 + lane;
      const int r = G >> 3, sl = G & 7;
      gload_lds16(Kb + (size_t)(kt * 64 + r) * 128 + ((sl ^ (r & 7)) * 16),
                  &Kl[G * 8]);
      gload_lds16(Vb + (size_t)r * 4096 + kt * 128 + ((sl ^ (r & 7)) * 16),
                  &Vl[G * 8]);
    }
  };

#pragma unroll
  for (int i = 0; i < 4; ++i) {
    const int G = (w * 4 + i) * 64 + lane;
    const int row = G >> 3, sl = G & 7;
    u16* qdst = (G < 512) ? (Sm + 4096) : (Sm + 12288);
    gload_lds16(Qb + (size_t)row * 128 + ((sl ^ (row & 7)) * 16),
                &qdst[(G & 511) * 8]);
  }
  stageKV(0, 0);
  __syncthreads();

  // Q fragment (B-operand of 32x32x16): q = l31, d = ds*16 + hi*8 + j
  const u16* qreg = (w < 2) ? (Sm + 4096) : (Sm + 12288);
  const int qr0 = (w & 1) * 32;
  short8 aq[4];
#pragma unroll
  for (int ds = 0; ds < 4; ++ds)
    aq[ds] = *(const short8*)&qreg[(qr0 + l31) * 64 + (((ds << 1) + hi) ^ l7) * 8];
  __syncthreads();

  f32x16 ot[2] = {};   // O^T acc: dt in {0,1}, d = dt*32 + (reg&3)+8*(reg>>2)+4*hi
  f32x2 l2 = {0.f, 0.f};

  for (int kt = 0; kt < 16; ++kt) {
    const int buf = kt & 1;
    if (kt < 15) stageKV(kt + 1, buf ^ 1);
    const u16* Kl = Sm + buf * 4096;
    const u16* Vl = Sm + 8192 + buf * 4096;

#pragma unroll
    for (int t = 0; t < 2; ++t) {  // two 32-k S^T tiles per 64-k LDS tile
      f32x16 st = {};
#pragma unroll
      for (int ds = 0; ds < 4; ++ds) {
        short8 kf = *(const short8*)&Kl[(t * 32 + l31) * 64 +
                                        (((ds << 1) + hi) ^ l7) * 8];
        st = mfma32(kf, aq[ds], st);
      }
      float e[16];
#pragma unroll
      for (int i = 0; i < 16; ++i) e[i] = __builtin_amdgcn_exp2f(st[i]);
#pragma unroll
      for (int i = 0; i < 8; ++i) l2 += (f32x2){e[2 * i], e[2 * i + 1]};

      // pack to PV B-fragments: pairing (e0,e1)x(e4,e5) etc per T12
      uint32_t p01 = cvtpk(e[0], e[1]),   p23 = cvtpk(e[2], e[3]);
      uint32_t p45 = cvtpk(e[4], e[5]),   p67 = cvtpk(e[6], e[7]);
      uint32_t p89 = cvtpk(e[8], e[9]),   pAB = cvtpk(e[10], e[11]);
      uint32_t pCD = cvtpk(e[12], e[13]), pEF = cvtpk(e[14], e[15]);
      permswap(p01, p45);  // -> ksub0 w0, w2
      permswap(p23, p67);  // -> ksub0 w1, w3
      permswap(p89, pCD);  // -> ksub1 w0, w2
      permswap(pAB, pEF);  // -> ksub1 w1, w3
      union { uint32_t u[4]; short8 s; } b0, b1;
      b0.u[0] = p01; b0.u[1] = p23; b0.u[2] = p45; b0.u[3] = p67;
      b1.u[0] = p89; b1.u[1] = pAB; b1.u[2] = pCD; b1.u[3] = pEF;

#pragma unroll
      for (int dt = 0; dt < 2; ++dt) {
#pragma unroll
        for (int s2 = 0; s2 < 2; ++s2) {
          short8 vf = *(const short8*)&Vl[(dt * 32 + l31) * 64 +
                                          ((((t * 2 + s2) << 1) + hi) ^ l7) * 8];
          ot[dt] = mfma32(vf, s2 ? b1.s : b0.s, ot[dt]);
        }
      }
    }
    if (kt < 15) __syncthreads();
  }

  // epilogue: packed o-partials + l-partials
  const int b = bh >> 4, h = bh & 15;
  u16* op = ks ? op1 : op0;
  float l = l2.x + l2.y;
  l += __shfl_xor(l, 32);
  const int srow = qt * 128 + w * 32 + l31;
  if (hi == 0) lp[((size_t)(ks * 32 + bh)) * 2048 + srow] = l;
  const int rt = b * 128 + qt * 8 + w * 2 + (l31 >> 4);  // row = rt*16 + (lane&15)
#pragma unroll
  for (int dt = 0; dt < 2; ++dt) {
    const int kc = h * 2 + dt;
#pragma unroll
    for (int g = 0; g < 4; ++g) {  // reg group: d = dt*32 + (reg&3) + 8*g + 4*hi
      const int ln = (lane & 15) + 16 * g;
      uint2 ov;
      ov.x = cvtpk(ot[dt][4 * g + 0], ot[dt][4 * g + 1]);
      ov.y = cvtpk(ot[dt][4 * g + 2], ot[dt][4 * g + 3]);
      *(uint2*)(op + ((size_t)((rt * 32 + kc) * 64 + ln)) * 8 + hi * 4) = ov;
    }
  }
}

// ---------- combine (packed granule-wise): awp = (o0+o1)/(l0+l1) ----------
__global__ void attn_combine(const u16* __restrict__ op0,
                             const u16* __restrict__ op1,
                             const float* __restrict__ lp,
                             u16* __restrict__ awp) {
  const int g = blockIdx.x * 256 + threadIdx.x;  // granule 0..524287
  const int ln = g & 63;
  const int kc = (g >> 6) & 31;
  const int rt = g >> 11;
  const int row = rt * 16 + (ln & 15);
  const int b = row >> 11, s = row & 2047;
  const int h = kc >> 1;
  const int lidx = (b * 16 + h) * 2048 + s;
  const float inv = __builtin_amdgcn_rcpf(lp[lidx] + lp[lidx + 65536]);
  const uint4 a0 = ((const uint4*)op0)[g];
  const uint4 a1 = ((const uint4*)op1)[g];
  uint4 o;
  o.x = pack2bf((bf2f(a0.x) + bf2f(a1.x)) * inv,
                (bf2f(a0.x >> 16) + bf2f(a1.x >> 16)) * inv);
  o.y = pack2bf((bf2f(a0.y) + bf2f(a1.y)) * inv,
                (bf2f(a0.y >> 16) + bf2f(a1.y >> 16)) * inv);
  o.z = pack2bf((bf2f(a0.z) + bf2f(a1.z)) * inv,
                (bf2f(a0.z >> 16) + bf2f(a1.z >> 16)) * inv);
  o.w = pack2bf((bf2f(a0.w) + bf2f(a1.w)) * inv,
                (bf2f(a0.w >> 16) + bf2f(a1.w >> 16)) * inv);
  ((uint4*)awp)[g] = o;
}

// ---------- LDS-staged out projection: C[4096,1024] f32 = aw @ Wo^T + bo ----------
// 128x128 block tile, 512 threads (8 waves of 64x32), 256 blocks = 2/CU.
__global__ __launch_bounds__(512, 2) void out_proj(const u16* __restrict__ awp,
                                                   const u16* __restrict__ wp,
                                                   const float* __restrict__ bo,
                                                   float* __restrict__ out) {
  __shared__ __align__(16) u16 As[8192];
  __shared__ __align__(16) u16 Bs[8192];
  const int tid = threadIdx.x, lane = tid & 63, w = tid >> 6;  // w 0..7
  const int quad = lane >> 4, l15 = lane & 15;

  const int bid = blockIdx.x;                    // 0..255
  const int work = (bid & 7) * 32 + (bid >> 3);  // bijective XCD chunk
  const int bm2 = work >> 3, bn2 = work & 7;     // 32 x 8 grid
  const int at0 = bm2 * 8, bt0 = 192 + bn2 * 8;  // Wo = wp tiles 192..255
  const int wr = w >> 2, wc = w & 3;             // wave tile 64x32

  f32x4 acc[4][2] = {};

  for (int ks = 0; ks < 16; ++ks) {
    const int kc0 = ks * 2;
#pragma unroll
    for (int i = 0; i < 4; ++i) {
      const int g = w * 4 + i;                   // 0..31
      const int gg = g & 15, t = gg >> 1, c = gg & 1;
      const u16* src = (g < 16)
          ? (awp + ((((at0 + t) << 5) + kc0 + c) * 64 + lane) * 8)
          : (wp + ((((bt0 + t) << 5) + kc0 + c) * 64 + lane) * 8);
      u16* dst = ((g < 16) ? As : Bs) + (gg * 64 + lane) * 8;
      gload_lds16(src, dst);
    }
    __syncthreads();

    short8 af[4][2], bf[2][2];
#pragma unroll
    for (int mt = 0; mt < 4; ++mt)
#pragma unroll
      for (int c = 0; c < 2; ++c)
        af[mt][c] = *(const short8*)&As[((((wr * 4 + mt) << 1) + c) * 64 + lane) * 8];
#pragma unroll
    for (int nt = 0; nt < 2; ++nt)
#pragma unroll
      for (int c = 0; c < 2; ++c)
        bf[nt][c] = *(const short8*)&Bs[((((wc * 2 + nt) << 1) + c) * 64 + lane) * 8];

#pragma unroll
    for (int c = 0; c < 2; ++c)
#pragma unroll
      for (int mt = 0; mt < 4; ++mt)
#pragma unroll
        for (int nt = 0; nt < 2; ++nt)
          acc[mt][nt] = mfma16(af[mt][c], bf[nt][c], acc[mt][nt]);
    __syncthreads();
  }

#pragma unroll
  for (int nt = 0; nt < 2; ++nt) {
    const int n = bn2 * 128 + wc * 32 + nt * 16 + l15;
    const float bb = bo[n];
#pragma unroll
    for (int mt = 0; mt < 4; ++mt)
#pragma unroll
      for (int r = 0; r < 4; ++r) {
        const int m = bm2 * 128 + wr * 64 + mt * 16 + quad * 4 + r;
        out[(size_t)m * 1024 + n] = acc[mt][nt][r] + bb;
      }
  }
}

// ---------- launch ----------
extern "C" void kernel_launch(void* const* d_in, const int* in_sizes, int n_in,
                              void* d_out, int out_size, void* d_ws, size_t ws_size,
                              hipStream_t stream) {
  const float* x  = (const float*)d_in[0];
  const float* Wq = (const float*)d_in[1];
  const float* bq = (const float*)d_in[2];
  const float* Wk = (const float*)d_in[3];
  const float* bk = (const float*)d_in[4];
  const float* Wv = (const float*)d_in[5];
  const float* bv = (const float*)d_in[6];
  const float* Wo = (const float*)d_in[7];
  const float* bo = (const float*)d_in[8];

  const size_t M4 = (size_t)4 * 1024 * 1024;
  u16* xp  = (u16*)d_ws;     // 4M elems; dead after proj -> reused as op0
  u16* wp  = xp + M4;        // packed [Wq;Wk;Wv;Wo]
  u16* qw  = wp + M4;
  u16* kw  = qw + M4;
  u16* vw  = kw + M4;
  u16* op1 = vw + M4;
  u16* awp = op1 + M4;
  float* lp = (float*)(awp + M4);  // 128K floats
  u16* op0 = xp;

  pack_all<<<4096, 256, 0, stream>>>(x, Wq, Wk, Wv, Wo, xp, wp);

  proj_qkv<<<768, 256, 0, stream>>>(xp, wp, bq, bk, bv, qw, kw, vw);

  attn_kernel<<<dim3(16, 64), 256, 0, stream>>>(qw, kw, vw, op0, op1, lp);

  attn_combine<<<2048, 256, 0, stream>>>(op0, op1, lp, awp);

  out_proj<<<256, 512, 0, stream>>>(awp, wp, bo, (float*)d_out);
}

// Round 3
// 187.562 us; speedup vs baseline: 1.1246x; 1.0283x over previous
//
#include <hip/hip_runtime.h>
#include <stdint.h>

typedef unsigned short u16;
typedef short short8 __attribute__((ext_vector_type(8)));
typedef float f32x4 __attribute__((ext_vector_type(4)));
typedef float f32x16 __attribute__((ext_vector_type(16)));
typedef float f32x2 __attribute__((ext_vector_type(2)));

// ---------- helpers ----------
__device__ __forceinline__ u16 f2bf_fast(float f) {
  union { float f; uint32_t u; } x;
  x.f = f;
  return (u16)((x.u + 0x8000u) >> 16);
}

__device__ __forceinline__ uint32_t pack2bf(float lo, float hi) {
  union { float f; uint32_t u; } a, b;
  a.f = lo; b.f = hi;
  return __builtin_amdgcn_perm(b.u + 0x8000u, a.u + 0x8000u, 0x07060302u);
}

__device__ __forceinline__ float bf2f(uint32_t u) {
  union { uint32_t u; float f; } x;
  x.u = u << 16;
  return x.f;
}

// v_cvt_pk_bf16_f32: D = {bf16(lo), bf16(hi)} (RNE). No builtin on gfx950.
__device__ __forceinline__ uint32_t cvtpk(float lo, float hi) {
  uint32_t r;
  asm("v_cvt_pk_bf16_f32 %0, %1, %2" : "=v"(r) : "v"(lo), "v"(hi));
  return r;
}

// v_permlane32_swap_b32: a.row1 <-> b.row0 (rows = 32-lane halves).
__device__ __forceinline__ void permswap(uint32_t& a, uint32_t& b) {
  asm("v_permlane32_swap_b32 %0, %1" : "+v"(a), "+v"(b));
}

__device__ __forceinline__ void gload_lds16(const void* g, void* l) {
  __builtin_amdgcn_global_load_lds(
      (const __attribute__((address_space(1))) void*)g,
      (__attribute__((address_space(3))) void*)l, 16, 0, 0);
}

__device__ __forceinline__ f32x4 mfma16(short8 a, short8 b, f32x4 c) {
  return __builtin_amdgcn_mfma_f32_16x16x32_bf16(a, b, c, 0, 0, 0);
}

__device__ __forceinline__ f32x16 mfma32(short8 a, short8 b, f32x16 c) {
  return __builtin_amdgcn_mfma_f32_32x32x16_bf16(a, b, c, 0, 0, 0);
}

#define QSCALE 0.18033688011112042f

// ---------- pack fp32 -> bf16 P32 fragment layout ----------
// P32: pack[((rt*32+kc)*64+ln)*8+j] = M[rt*16+(ln&15)][kc*32+(ln>>4)*8+j]
// rt 0..255 -> x (4096x1024) into xp; rt 256..511 -> [Wq;Wk;Wv;Wo] into wp.
__global__ void pack_all(const float* __restrict__ x, const float* __restrict__ wq,
                         const float* __restrict__ wk, const float* __restrict__ wv,
                         const float* __restrict__ wo, u16* __restrict__ xp,
                         u16* __restrict__ wp) {
  const int gi = blockIdx.x * 256 + threadIdx.x;  // granule id, 0..1048575
  const int lane = gi & 63;
  const int kc = (gi >> 6) & 31;
  const int rt = gi >> 11;  // row tile 0..511
  const int col = kc * 32 + (lane >> 4) * 8;
  const float* src;
  int row;
  if (rt < 256) {
    src = x;
    row = rt * 16 + (lane & 15);
  } else {
    const int wti = rt - 256;             // 0..255
    const int widx = wti >> 6;            // which weight
    src = (widx == 0) ? wq : (widx == 1) ? wk : (widx == 2) ? wv : wo;
    row = (wti & 63) * 16 + (lane & 15);
  }
  const float4* p = (const float4*)(src + (size_t)row * 1024 + col);
  const float4 v0 = p[0], v1 = p[1];
  uint4 o;
  o.x = pack2bf(v0.x, v0.y);
  o.y = pack2bf(v0.z, v0.w);
  o.z = pack2bf(v1.x, v1.y);
  o.w = pack2bf(v1.z, v1.w);
  u16* dst = (rt < 256) ? xp : wp;
  const int og = (rt < 256) ? gi : gi - 524288;
  ((uint4*)dst)[og] = o;
}

// ---------- LDS-staged 128x128 projection GEMM, min-2-phase dbuf ----------
// BK=32 (1 kc-granule), two 16KB buffers per operand half; per step:
// issue next-step gload_lds, compute current from the other buffer, one
// __syncthreads per step (full drain). Staging flies under ds_read+MFMA.
// works 0..511:  QK: C = x @ [Wq|Wk]^T, block (bm2 0..31, bn2 0..15).
// works 512..767: V: C = Wv @ x^T,      block (bm2 0..7,  bn2 0..31).
__global__ __launch_bounds__(256, 3) void proj_qkv(
    const u16* __restrict__ xp, const u16* __restrict__ wp,
    const float* __restrict__ bq, const float* __restrict__ bk,
    const float* __restrict__ bv, u16* __restrict__ qw, u16* __restrict__ kw,
    u16* __restrict__ vw) {
  __shared__ __align__(16) u16 As[8192];   // 2 bufs x (8 row-tiles x 1 kc)
  __shared__ __align__(16) u16 Bs[8192];
  const int tid = threadIdx.x, lane = tid & 63, w = tid >> 6;
  const int quad = lane >> 4, l15 = lane & 15;

  // bijective XCD-chunked swizzle: 768 blocks, 96 per XCD
  const int bid = blockIdx.x;
  const int work = (bid & 7) * 96 + (bid >> 3);
  const bool isQK = work < 512;
  int at0, bt0, bm2, bn2;
  const u16 *Ap, *Bp;
  if (isQK) {
    bm2 = work >> 4; bn2 = work & 15;          // bm-major: B panel L2-resident
    Ap = xp; at0 = bm2 * 8;
    Bp = wp; bt0 = bn2 * 8;                    // Wq|Wk tiles 0..127
  } else {
    const int h = work - 512;
    bm2 = h >> 5; bn2 = h & 31;
    Ap = wp; at0 = 128 + bm2 * 8;              // Wv tiles 128..191
    Bp = xp; bt0 = bn2 * 8;                    // x row-tiles (seq)
  }
  const int wr = w >> 1, wc = w & 1;
  const int bm = bm2 * 2 + wr, bn = bn2 * 2 + wc;  // 64-row/col units

  // stage one kc (32-deep K slice): 16 granules, 4 per wave
  auto stage = [&](int kc, int buf) {
#pragma unroll
    for (int i = 0; i < 4; ++i) {
      const int g = w * 4 + i;                 // 0..15
      const int t = g & 7;
      const u16* src = (g < 8)
          ? (Ap + (((at0 + t) << 5) + kc) * 512 + lane * 8)
          : (Bp + (((bt0 + t) << 5) + kc) * 512 + lane * 8);
      u16* dst = ((g < 8) ? As : Bs) + (buf * 8 + t) * 512 + lane * 8;
      gload_lds16(src, dst);
    }
  };

  f32x4 acc[4][4] = {};

  stage(0, 0);
  __syncthreads();

  for (int kc = 0; kc < 32; ++kc) {
    const int cur = kc & 1;
    if (kc < 31) stage(kc + 1, cur ^ 1);

    const u16* Ab = As + cur * 4096;
    const u16* Bb = Bs + cur * 4096;
    short8 af[4], bf[4];
#pragma unroll
    for (int mt = 0; mt < 4; ++mt)
      af[mt] = *(const short8*)&Ab[((wr * 4 + mt) * 64 + lane) * 8];
#pragma unroll
    for (int nt = 0; nt < 4; ++nt)
      bf[nt] = *(const short8*)&Bb[((wc * 4 + nt) * 64 + lane) * 8];

#pragma unroll
    for (int mt = 0; mt < 4; ++mt)
#pragma unroll
      for (int nt = 0; nt < 4; ++nt)
        acc[mt][nt] = mfma16(af[mt], bf[nt], acc[mt][nt]);
    __syncthreads();   // drains vmcnt (next buf staged) + readers done
  }

#pragma unroll
  for (int nt = 0; nt < 4; ++nt) {
    const int n = bn * 64 + nt * 16 + l15;
#pragma unroll
    for (int mt = 0; mt < 4; ++mt)
#pragma unroll
      for (int r = 0; r < 4; ++r) {
        const int m = bm * 64 + mt * 16 + quad * 4 + r;
        const float a = acc[mt][nt][r];
        if (isQK) {
          const bool isQ = (bn < 16);
          const int nn = isQ ? n : n - 1024;
          const float v = isQ ? (a + bq[nn]) * QSCALE : a + bk[nn];
          u16* op = isQ ? qw : kw;
          const int b = m >> 11, s = m & 2047, hh = nn >> 6, d = nn & 63;
          op[((size_t)((b * 16 + hh) * 2048 + s)) * 64 + d] = f2bf_fast(v);
        } else {
          const float v = a + bv[m];
          const int b = n >> 11, s = n & 2047;
          vw[((size_t)(b * 1024 + m)) * 2048 + s] = f2bf_fast(v);
        }
      }
  }
}

// ---------- flash attention, 32x32-MFMA, full-K (no ks split) ----------
// Each block owns (qt, bh) and loops all 32 K-tiles; normalizes in the
// epilogue and writes the packed aw granules directly (no combine pass).
__global__ __launch_bounds__(256, 4) void attn_kernel(
    const u16* __restrict__ Q, const u16* __restrict__ Kt,
    const u16* __restrict__ Vt, u16* __restrict__ awp) {
  __shared__ __align__(16) u16 Sm[16384];  // 32 KB
  const int tid = threadIdx.x, lane = tid & 63, w = tid >> 6;
  const int l31 = lane & 31, hi = lane >> 5, l7 = lane & 7;
  const int qt = blockIdx.x;
  const int bh = blockIdx.y;

  const char* Qb = (const char*)(Q + ((size_t)bh * 2048 + qt * 128) * 64);
  const char* Kb = (const char*)(Kt + (size_t)bh * 2048 * 64);
  const char* Vb = (const char*)(Vt + (size_t)bh * 64 * 2048);

  auto stageKV = [&](int kt, int b) {
    u16* Kl = Sm + b * 4096;
    u16* Vl = Sm + 8192 + b * 4096;
#pragma unroll
    for (int i = 0; i < 2; ++i) {
      const int G = (w * 2 + i) * 64 + lane;
      const int r = G >> 3, sl = G & 7;
      gload_lds16(Kb + (size_t)(kt * 64 + r) * 128 + ((sl ^ (r & 7)) * 16),
                  &Kl[G * 8]);
      gload_lds16(Vb + (size_t)r * 4096 + kt * 128 + ((sl ^ (r & 7)) * 16),
                  &Vl[G * 8]);
    }
  };

#pragma unroll
  for (int i = 0; i < 4; ++i) {
    const int G = (w * 4 + i) * 64 + lane;
    const int row = G >> 3, sl = G & 7;
    u16* qdst = (G < 512) ? (Sm + 4096) : (Sm + 12288);
    gload_lds16(Qb + (size_t)row * 128 + ((sl ^ (row & 7)) * 16),
                &qdst[(G & 511) * 8]);
  }
  stageKV(0, 0);
  __syncthreads();

  // Q fragment (B-operand of 32x32x16): q = l31, d = ds*16 + hi*8 + j
  const u16* qreg = (w < 2) ? (Sm + 4096) : (Sm + 12288);
  const int qr0 = (w & 1) * 32;
  short8 aq[4];
#pragma unroll
  for (int ds = 0; ds < 4; ++ds)
    aq[ds] = *(const short8*)&qreg[(qr0 + l31) * 64 + (((ds << 1) + hi) ^ l7) * 8];
  __syncthreads();

  f32x16 ot[2] = {};   // O^T acc: dt in {0,1}, d = dt*32 + (reg&3)+8*(reg>>2)+4*hi
  f32x2 l2 = {0.f, 0.f};

  for (int kt = 0; kt < 32; ++kt) {
    const int buf = kt & 1;
    if (kt < 31) stageKV(kt + 1, buf ^ 1);
    const u16* Kl = Sm + buf * 4096;
    const u16* Vl = Sm + 8192 + buf * 4096;

#pragma unroll
    for (int t = 0; t < 2; ++t) {  // two 32-k S^T tiles per 64-k LDS tile
      f32x16 st = {};
      __builtin_amdgcn_s_setprio(1);
#pragma unroll
      for (int ds = 0; ds < 4; ++ds) {
        short8 kf = *(const short8*)&Kl[(t * 32 + l31) * 64 +
                                        (((ds << 1) + hi) ^ l7) * 8];
        st = mfma32(kf, aq[ds], st);
      }
      __builtin_amdgcn_s_setprio(0);
      float e[16];
#pragma unroll
      for (int i = 0; i < 16; ++i) e[i] = __builtin_amdgcn_exp2f(st[i]);
#pragma unroll
      for (int i = 0; i < 8; ++i) l2 += (f32x2){e[2 * i], e[2 * i + 1]};

      // pack to PV B-fragments: pairing (e0,e1)x(e4,e5) etc per T12
      uint32_t p01 = cvtpk(e[0], e[1]),   p23 = cvtpk(e[2], e[3]);
      uint32_t p45 = cvtpk(e[4], e[5]),   p67 = cvtpk(e[6], e[7]);
      uint32_t p89 = cvtpk(e[8], e[9]),   pAB = cvtpk(e[10], e[11]);
      uint32_t pCD = cvtpk(e[12], e[13]), pEF = cvtpk(e[14], e[15]);
      permswap(p01, p45);  // -> ksub0 w0, w2
      permswap(p23, p67);  // -> ksub0 w1, w3
      permswap(p89, pCD);  // -> ksub1 w0, w2
      permswap(pAB, pEF);  // -> ksub1 w1, w3
      union { uint32_t u[4]; short8 s; } b0, b1;
      b0.u[0] = p01; b0.u[1] = p23; b0.u[2] = p45; b0.u[3] = p67;
      b1.u[0] = p89; b1.u[1] = pAB; b1.u[2] = pCD; b1.u[3] = pEF;

      __builtin_amdgcn_s_setprio(1);
#pragma unroll
      for (int dt = 0; dt < 2; ++dt) {
#pragma unroll
        for (int s2 = 0; s2 < 2; ++s2) {
          short8 vf = *(const short8*)&Vl[(dt * 32 + l31) * 64 +
                                          ((((t * 2 + s2) << 1) + hi) ^ l7) * 8];
          ot[dt] = mfma32(vf, s2 ? b1.s : b0.s, ot[dt]);
        }
      }
      __builtin_amdgcn_s_setprio(0);
    }
    if (kt < 31) __syncthreads();
  }

  // epilogue: normalize and write packed aw granules directly
  const int b = bh >> 4, h = bh & 15;
  float l = l2.x + l2.y;
  l += __shfl_xor(l, 32);
  const float inv = __builtin_amdgcn_rcpf(l);
  const int rt = b * 128 + qt * 8 + w * 2 + (l31 >> 4);  // row = rt*16 + (lane&15)
#pragma unroll
  for (int dt = 0; dt < 2; ++dt) {
    const int kc = h * 2 + dt;
#pragma unroll
    for (int g = 0; g < 4; ++g) {  // reg group: d = dt*32 + (reg&3) + 8*g + 4*hi
      const int ln = (lane & 15) + 16 * g;
      uint2 ov;
      ov.x = cvtpk(ot[dt][4 * g + 0] * inv, ot[dt][4 * g + 1] * inv);
      ov.y = cvtpk(ot[dt][4 * g + 2] * inv, ot[dt][4 * g + 3] * inv);
      *(uint2*)(awp + ((size_t)((rt * 32 + kc) * 64 + ln)) * 8 + hi * 4) = ov;
    }
  }
}

// ---------- LDS-staged out projection, min-2-phase dbuf ----------
// C[4096,1024] f32 = aw @ Wo^T + bo. 128x128 tile, 512 threads (8 waves
// of 64x32), BK=32 double-buffered.
__global__ __launch_bounds__(512, 2) void out_proj(const u16* __restrict__ awp,
                                                   const u16* __restrict__ wp,
                                                   const float* __restrict__ bo,
                                                   float* __restrict__ out) {
  __shared__ __align__(16) u16 As[8192];
  __shared__ __align__(16) u16 Bs[8192];
  const int tid = threadIdx.x, lane = tid & 63, w = tid >> 6;  // w 0..7
  const int quad = lane >> 4, l15 = lane & 15;

  const int bid = blockIdx.x;                    // 0..255
  const int work = (bid & 7) * 32 + (bid >> 3);  // bijective XCD chunk
  const int bm2 = work >> 3, bn2 = work & 7;     // 32 x 8 grid
  const int at0 = bm2 * 8, bt0 = 192 + bn2 * 8;  // Wo = wp tiles 192..255
  const int wr = w >> 2, wc = w & 3;             // wave tile 64x32

  auto stage = [&](int kc, int buf) {
#pragma unroll
    for (int i = 0; i < 2; ++i) {
      const int g = w * 2 + i;                   // 0..15
      const int t = g & 7;
      const u16* src = (g < 8)
          ? (awp + (((at0 + t) << 5) + kc) * 512 + lane * 8)
          : (wp + (((bt0 + t) << 5) + kc) * 512 + lane * 8);
      u16* dst = ((g < 8) ? As : Bs) + (buf * 8 + t) * 512 + lane * 8;
      gload_lds16(src, dst);
    }
  };

  f32x4 acc[4][2] = {};

  stage(0, 0);
  __syncthreads();

  for (int kc = 0; kc < 32; ++kc) {
    const int cur = kc & 1;
    if (kc < 31) stage(kc + 1, cur ^ 1);

    const u16* Ab = As + cur * 4096;
    const u16* Bb = Bs + cur * 4096;
    short8 af[4], bf[2];
#pragma unroll
    for (int mt = 0; mt < 4; ++mt)
      af[mt] = *(const short8*)&Ab[((wr * 4 + mt) * 64 + lane) * 8];
#pragma unroll
    for (int nt = 0; nt < 2; ++nt)
      bf[nt] = *(const short8*)&Bb[((wc * 2 + nt) * 64 + lane) * 8];

#pragma unroll
    for (int mt = 0; mt < 4; ++mt)
#pragma unroll
      for (int nt = 0; nt < 2; ++nt)
        acc[mt][nt] = mfma16(af[mt], bf[nt], acc[mt][nt]);
    __syncthreads();
  }

#pragma unroll
  for (int nt = 0; nt < 2; ++nt) {
    const int n = bn2 * 128 + wc * 32 + nt * 16 + l15;
    const float bb = bo[n];
#pragma unroll
    for (int mt = 0; mt < 4; ++mt)
#pragma unroll
      for (int r = 0; r < 4; ++r) {
        const int m = bm2 * 128 + wr * 64 + mt * 16 + quad * 4 + r;
        out[(size_t)m * 1024 + n] = acc[mt][nt][r] + bb;
      }
  }
}

// ---------- launch ----------
extern "C" void kernel_launch(void* const* d_in, const int* in_sizes, int n_in,
                              void* d_out, int out_size, void* d_ws, size_t ws_size,
                              hipStream_t stream) {
  const float* x  = (const float*)d_in[0];
  const float* Wq = (const float*)d_in[1];
  const float* bq = (const float*)d_in[2];
  const float* Wk = (const float*)d_in[3];
  const float* bk = (const float*)d_in[4];
  const float* Wv = (const float*)d_in[5];
  const float* bv = (const float*)d_in[6];
  const float* Wo = (const float*)d_in[7];
  const float* bo = (const float*)d_in[8];

  const size_t M4 = (size_t)4 * 1024 * 1024;
  u16* xp  = (u16*)d_ws;
  u16* wp  = xp + M4;        // packed [Wq;Wk;Wv;Wo]
  u16* qw  = wp + M4;
  u16* kw  = qw + M4;
  u16* vw  = kw + M4;
  u16* awp = vw + M4;

  pack_all<<<4096, 256, 0, stream>>>(x, Wq, Wk, Wv, Wo, xp, wp);

  proj_qkv<<<768, 256, 0, stream>>>(xp, wp, bq, bk, bv, qw, kw, vw);

  attn_kernel<<<dim3(16, 32), 256, 0, stream>>>(qw, kw, vw, awp);

  out_proj<<<256, 512, 0, stream>>>(awp, wp, bo, (float*)d_out);
}